// Round 3
// baseline (105.915 us; speedup 1.0000x reference)
//
#include <hip/hip_runtime.h>

namespace {
constexpr int Bn = 8, Cn = 256, Hn = 96, Wn = 128;
constexpr int HWn = Hn * Wn;            // 12288
constexpr int CHWn = Cn * HWn;
constexpr int ND = 9;                   // 2*MD+1
constexpr int TILESH = Hn / 4;          // 24 tiles of 4 h-rows
constexpr int NBLK = Bn * TILESH * ND;  // 1728 one-wave blocks
constexpr int PERX = NBLK / 8;          // 216 blocks/XCD -> one batch image per XCD
}

// DPP lane shifts within 16-lane rows; bound_ctrl=true -> shifted-in lanes read 0
// (this IS the w-direction zero padding at tile edges).
__device__ __forceinline__ float dpp_shr1(float x) {  // lane i <- lane i-1 (row-local)
  return __int_as_float(__builtin_amdgcn_update_dpp(
      0, __float_as_int(x), 0x111 /*row_shr:1*/, 0xF, 0xF, true));
}
__device__ __forceinline__ float dpp_shl1(float x) {  // lane i <- lane i+1 (row-local)
  return __int_as_float(__builtin_amdgcn_update_dpp(
      0, __float_as_int(x), 0x101 /*row_shl:1*/, 0xF, 0xF, true));
}

struct Ch {
  float4 sa, sb, fa, fb;
};

__global__ __launch_bounds__(64, 2) void corr_kernel(
    const float* __restrict__ first, const float* __restrict__ second,
    float* __restrict__ out)
{
  const int lane = threadIdx.x;
  const int bid = blockIdx.x;
  // XCD-aware swizzle: XCD x handles batch image b=x -> second re-reads stay in its L2.
  const int logical = (bid & 7) * PERX + (bid >> 3);
  const int dy = logical % ND;
  const int t = logical / ND;
  const int b = t / TILESH;
  const int h0 = (t % TILESH) * 4;

  const int hs = lane >> 4;          // 0..3: h-row within tile (= DPP row group)
  const int w0 = (lane & 15) << 3;   // 0..120: 8 pixels per lane

  const int gr = h0 + hs + dy - 4;                    // second source row
  const float m = (gr >= 0 && gr < Hn) ? 1.0f : 0.0f; // uniform within each 16-lane row
  const int cg = min(max(gr, 0), Hn - 1);             // clamped (safe) row

  const float* ssrc = second + b * CHWn + cg * Wn + w0;
  const float* fsrc = first + b * CHWn + (h0 + hs) * Wn + w0;

  float acc[ND][8];
#pragma unroll
  for (int dx = 0; dx < ND; ++dx)
#pragma unroll
    for (int p = 0; p < 8; ++p) acc[dx][p] = 0.f;

  auto LOADCH = [&](int coff) -> Ch {
    Ch r;
    r.sa = *(const float4*)(ssrc + coff);
    r.sb = *(const float4*)(ssrc + coff + 4);
    r.fa = *(const float4*)(fsrc + coff);
    r.fb = *(const float4*)(fsrc + coff + 4);
    return r;
  };

  auto COMP = [&](const Ch& ch) {
    // mask second row (OOB rows -> 0), BEFORE the lane shifts (m is row-uniform)
    const float sa0 = ch.sa.x * m, sa1 = ch.sa.y * m, sa2 = ch.sa.z * m, sa3 = ch.sa.w * m;
    const float sb0 = ch.sb.x * m, sb1 = ch.sb.y * m, sb2 = ch.sb.z * m, sb3 = ch.sb.w * m;
    // 16-float window cols w0-4 .. w0+11: halos from neighbor lanes via DPP
    const float s[16] = {
        dpp_shr1(sb0), dpp_shr1(sb1), dpp_shr1(sb2), dpp_shr1(sb3),
        sa0, sa1, sa2, sa3,
        sb0, sb1, sb2, sb3,
        dpp_shl1(sa0), dpp_shl1(sa1), dpp_shl1(sa2), dpp_shl1(sa3)};
    const float f[8] = {ch.fa.x, ch.fa.y, ch.fa.z, ch.fa.w,
                        ch.fb.x, ch.fb.y, ch.fb.z, ch.fb.w};
#pragma unroll
    for (int dx = 0; dx < ND; ++dx)
#pragma unroll
      for (int p = 0; p < 8; ++p)
        acc[dx][p] = fmaf(f[p], s[p + dx], acc[dx][p]);
  };

  // depth-4 interleaved register pipeline: 4 channels in flight; each load has
  // ~3 COMP blocks (~950+ aggregate cycles) of lookahead before consumption.
  Ch L0 = LOADCH(0);
  Ch L1 = LOADCH(HWn);
  Ch L2 = LOADCH(2 * HWn);
  Ch L3 = LOADCH(3 * HWn);
  int coff = 4 * HWn;
#pragma unroll 1
  for (int it = 0; it < (Cn - 4) / 4; ++it) {  // 63 iters, computes c=0..251
    Ch N0 = LOADCH(coff);
    COMP(L0);
    Ch N1 = LOADCH(coff + HWn);
    COMP(L1);
    Ch N2 = LOADCH(coff + 2 * HWn);
    COMP(L2);
    Ch N3 = LOADCH(coff + 3 * HWn);
    COMP(L3);
    L0 = N0; L1 = N1; L2 = N2; L3 = N3;
    coff += 4 * HWn;
  }
  COMP(L0);  // c = 252
  COMP(L1);  // c = 253
  COMP(L2);  // c = 254
  COMP(L3);  // c = 255

  const float sc = 1.0f / Cn;
  float* obase = out + ((b * 81 + dy * ND) * Hn + (h0 + hs)) * Wn + w0;
#pragma unroll
  for (int dx = 0; dx < ND; ++dx) {
    float4 o0 = make_float4(acc[dx][0] * sc, acc[dx][1] * sc,
                            acc[dx][2] * sc, acc[dx][3] * sc);
    float4 o1 = make_float4(acc[dx][4] * sc, acc[dx][5] * sc,
                            acc[dx][6] * sc, acc[dx][7] * sc);
    *(float4*)(obase + dx * HWn) = o0;
    *(float4*)(obase + dx * HWn + 4) = o1;
  }
}

extern "C" void kernel_launch(void* const* d_in, const int* in_sizes, int n_in,
                              void* d_out, int out_size, void* d_ws, size_t ws_size,
                              hipStream_t stream) {
  const float* first = (const float*)d_in[0];
  const float* second = (const float*)d_in[1];
  float* out = (float*)d_out;
  corr_kernel<<<dim3(NBLK), dim3(64), 0, stream>>>(first, second, out);
}